// Round 4
// baseline (371.391 us; speedup 1.0000x reference)
//
#include <hip/hip_runtime.h>

// QRNN: SEQ=4096, BATCH=8, CIN=256, HID=256, K=2 (lookback=1)
// R4: 128x256 GEMM tiles (64 MFMA/barrier/wave, 2 blocks/CU), fused
//     scanA+B+C into one kernel with device-scope grid barrier (z/f in regs).
//
// ws: zbf 16MB | fbf 16MB | Xbf 16MB (dead after gemm; Ac/Cc/Hs aliased) | Bm 0.5MB | bar

#define SEQn 4096
#define NCH 2048          // BATCH*HID channels
#define CHUNK 32
#define NCHUNK 128

typedef __attribute__((ext_vector_type(8))) short bf16x8;
typedef __attribute__((ext_vector_type(4))) float floatx4;

__device__ __forceinline__ unsigned short f2bf(float x) {
  unsigned int u = __float_as_uint(x);
  u += 0x7fffu + ((u >> 16) & 1u);     // RNE
  return (unsigned short)(u >> 16);
}
__device__ __forceinline__ float bf2f_lo(unsigned int v) {
  return __uint_as_float(v << 16);
}
__device__ __forceinline__ float bf2f_hi(unsigned int v) {
  return __uint_as_float(v & 0xffff0000u);
}
__device__ __forceinline__ float sigf(float x) {
  return __builtin_amdgcn_rcpf(1.0f + __expf(-x));
}

// ---- 1) merged pack: blocks [0,1024) pack W, rest pack X; also zero barrier ----
__global__ void pack_kernel(const float* __restrict__ X,
                            const float* __restrict__ Wz, const float* __restrict__ Wf,
                            ushort* __restrict__ Xbf, ushort* __restrict__ Bm,
                            unsigned* __restrict__ bar) {
  if (blockIdx.x == 0 && threadIdx.x == 0) { bar[0] = 0; bar[1] = 0; }
  if (blockIdx.x < 1024) {
    int idx = blockIdx.x * 256 + threadIdx.x;        // 0..262143
    int n = idx >> 9, kin = idx & 511;
    const float* W = (n < 256) ? Wz : Wf;
    int h = n & 255, c = kin & 255, tap = kin >> 8;  // kin<256: tap0 (X[s-1])
    Bm[idx] = f2bf(W[h * 512 + c * 2 + tap]);
  } else {
    int idx = (blockIdx.x - 1024) * 256 + threadIdx.x;
    const int total4 = ((SEQn + 1) * NCH) / 4;       // 2,097,664
    if (idx >= total4) return;
    const int pad4 = NCH / 4;
    float4 v;
    if (idx < pad4) { v.x = 0.f; v.y = 0.f; v.z = 0.f; v.w = 0.f; }
    else v = ((const float4*)X)[idx - pad4];
    ushort4 o;
    o.x = f2bf(v.x); o.y = f2bf(v.y); o.z = f2bf(v.z); o.w = f2bf(v.w);
    ((ushort4*)Xbf)[idx] = o;
  }
}

// ---- 2) GEMM 128x256 tile, BK=64, mfma_f32_16x16x32_bf16, swizzled LDS ----
// grid (256, 2): bn=0 -> Z (Bm rows 0..255), bn=1 -> F (Bm rows 256..511)
__global__ __launch_bounds__(256, 2) void gemm_kernel(
    const ushort* __restrict__ Xbf, const ushort* __restrict__ Bm,
    const float* __restrict__ bz, const float* __restrict__ bfb,
    ushort* __restrict__ zout, ushort* __restrict__ fout) {
  __shared__ __align__(16) char smem_raw[49152];
  ushort* sA = (ushort*)smem_raw;                 // 128 rows x 64 k
  ushort* sB = (ushort*)(smem_raw + 16384);       // 256 rows x 64 k
  ushort* sT = (ushort*)smem_raw;                 // epilogue 64 x 264

  const int tid  = threadIdx.x;
  const int wave = tid >> 6;
  const int lane = tid & 63;
  const int quad = lane >> 4;
  const int lrow = lane & 15;
  const int wm = wave >> 1;          // 2x2 waves, each 64m x 128n
  const int wn = wave & 1;
  const int bm = blockIdx.x;         // 0..255
  const int bn = blockIdx.y;         // 0:Z 1:F

  floatx4 acc[4][8];
#pragma unroll
  for (int i = 0; i < 4; ++i)
#pragma unroll
    for (int j = 0; j < 8; ++j)
      acc[i][j] = (floatx4){0.f, 0.f, 0.f, 0.f};

  // A staging: 1024 segs (128 rows x 8), 4/thread; LDS holds global seg s^(row&7) at slot s
  int offA[4], koA[4];
#pragma unroll
  for (int it = 0; it < 4; ++it) {
    int g = wave * 256 + it * 64 + lane;
    int row = g >> 3;
    koA[it] = ((g & 7) ^ (row & 7)) * 8;
    offA[it] = (bm * 128 + row) * 256;
  }
  // B staging: 2048 segs (256 rows x 8), 8/thread
  int offB[8];
#pragma unroll
  for (int it = 0; it < 8; ++it) {
    int g = wave * 512 + it * 64 + lane;
    int row = g >> 3;
    offB[it] = (bn * 256 + row) * 512 + ((g & 7) ^ (row & 7)) * 8;
  }
  char* ldsA = smem_raw + wave * 4096 + (lane << 4);
  char* ldsB = smem_raw + 16384 + wave * 8192 + (lane << 4);

  for (int k0 = 0; k0 < 512; k0 += 64) {
    __syncthreads();                 // prev iter ds_reads done
#pragma unroll
    for (int it = 0; it < 4; ++it) {
      const int kk = k0 + koA[it];
      const int cA = (kk < 256) ? kk : kk + 1792;     // tap1 lives +2048-256
      __builtin_amdgcn_global_load_lds(
          (const __attribute__((address_space(1))) void*)(Xbf + offA[it] + cA),
          (__attribute__((address_space(3))) void*)(ldsA + it * 1024), 16, 0, 0);
    }
#pragma unroll
    for (int it = 0; it < 8; ++it) {
      __builtin_amdgcn_global_load_lds(
          (const __attribute__((address_space(1))) void*)(Bm + offB[it] + k0),
          (__attribute__((address_space(3))) void*)(ldsB + it * 1024), 16, 0, 0);
    }
    __syncthreads();

#pragma unroll
    for (int ks = 0; ks < 2; ++ks) {
      bf16x8 af[4], bfr[8];
#pragma unroll
      for (int fi = 0; fi < 4; ++fi) {
        const int r = wm * 64 + fi * 16 + lrow;
        const int s = (ks * 4 + quad) ^ (r & 7);
        af[fi] = *(const bf16x8*)&sA[r * 64 + s * 8];
      }
#pragma unroll
      for (int fj = 0; fj < 8; ++fj) {
        const int r = wn * 128 + fj * 16 + lrow;
        const int s = (ks * 4 + quad) ^ (r & 7);
        bfr[fj] = *(const bf16x8*)&sB[r * 64 + s * 8];
      }
#pragma unroll
      for (int fi = 0; fi < 4; ++fi)
#pragma unroll
        for (int fj = 0; fj < 8; ++fj)
          acc[fi][fj] = __builtin_amdgcn_mfma_f32_16x16x32_bf16(af[fi], bfr[fj], acc[fi][fj], 0, 0, 0);
    }
  }

  // epilogue: activation -> bf16 -> sT (64 x 264 padded) -> coalesced dwordx4
  const bool isZ = (bn == 0);
  ushort* gout = isZ ? zout : fout;
  const float* bias = isZ ? bz : bfb;
  float bv[8];
#pragma unroll
  for (int fj = 0; fj < 8; ++fj)
    bv[fj] = bias[wn * 128 + fj * 16 + lrow];

  for (int round = 0; round < 2; ++round) {
    __syncthreads();
    if (wm == round) {
#pragma unroll
      for (int fi = 0; fi < 4; ++fi)
#pragma unroll
        for (int fj = 0; fj < 8; ++fj)
#pragma unroll
        for (int r = 0; r < 4; ++r) {
          float v = acc[fi][fj][r] + bv[fj];
          float o = isZ ? (v * sigf(1.702f * v)) : sigf(v);
          sT[(fi * 16 + quad * 4 + r) * 264 + wn * 128 + fj * 16 + lrow] = f2bf(o);
        }
    }
    __syncthreads();
#pragma unroll
    for (int it = 0; it < 8; ++it) {
      int e = tid + it * 256;           // 2048 segs = 64 rows x 32 segs
      int row = e >> 5, seg = e & 31;
      uint4 v = *(uint4*)&sT[row * 264 + seg * 8];
      *(uint4*)(gout + (size_t)(bm * 128 + round * 64 + row) * 256 + seg * 8) = v;
    }
  }
}

// ---- device-scope grid barrier (grid=256 <= 1 block/CU: all resident) ----
__device__ __forceinline__ void gridbar(unsigned* ctr, unsigned target) {
  __syncthreads();
  if (threadIdx.x == 0) {
    __hip_atomic_fetch_add(ctr, 1u, __ATOMIC_ACQ_REL, __HIP_MEMORY_SCOPE_AGENT);
    while (__hip_atomic_load(ctr, __ATOMIC_ACQUIRE, __HIP_MEMORY_SCOPE_AGENT) < target)
      __builtin_amdgcn_s_sleep(8);
  }
  __syncthreads();
}

// ---- 3) fused scan: 256 blocks x 512 threads, z/f stay in registers ----
__global__ __launch_bounds__(512, 2) void scan_kernel(
    const ushort* __restrict__ z, const ushort* __restrict__ f,
    const float* __restrict__ hidden,
    float* __restrict__ Ac, float* __restrict__ Cc, float* __restrict__ Hs,
    float* __restrict__ out, unsigned* __restrict__ bar) {
  const int tid = threadIdx.x;
  const int t = blockIdx.x * 512 + tid;            // 0..131071
  const int ch2 = t & 1023;                         // channel pair
  const int j = t >> 10;                            // chunk 0..127
  const size_t base = (size_t)j * CHUNK * NCH + 2 * ch2;

  // phase A: load z,f (32 steps x 2 ch) into regs; per-chunk (A,C)
  unsigned zr[CHUNK], fr[CHUNK];
  float A0 = 1.0f, C0 = 0.0f, A1 = 1.0f, C1 = 0.0f;
#pragma unroll
  for (int i = 0; i < CHUNK; ++i) {
    unsigned fv = *(const unsigned*)(f + base + (size_t)i * NCH);
    unsigned zv = *(const unsigned*)(z + base + (size_t)i * NCH);
    fr[i] = fv; zr[i] = zv;
    float f0 = bf2f_lo(fv), f1 = bf2f_hi(fv);
    float a0 = 1.0f - f0, a1 = 1.0f - f1;
    C0 = fmaf(a0, C0, f0 * bf2f_lo(zv)); A0 *= a0;
    C1 = fmaf(a1, C1, f1 * bf2f_hi(zv)); A1 *= a1;
  }
  {
    const size_t o = (size_t)j * NCH + 2 * ch2;
    __hip_atomic_store(Ac + o,     A0, __ATOMIC_RELEASE, __HIP_MEMORY_SCOPE_AGENT);
    __hip_atomic_store(Ac + o + 1, A1, __ATOMIC_RELEASE, __HIP_MEMORY_SCOPE_AGENT);
    __hip_atomic_store(Cc + o,     C0, __ATOMIC_RELEASE, __HIP_MEMORY_SCOPE_AGENT);
    __hip_atomic_store(Cc + o + 1, C1, __ATOMIC_RELEASE, __HIP_MEMORY_SCOPE_AGENT);
  }
  gridbar(bar, 256);

  // phase B: 2048 waves = 2048 channels; shfl Hillis-Steele over 128 chunks
  {
    const int lane = tid & 63;
    const int ch = blockIdx.x * 8 + (tid >> 6);
    const int j0 = 2 * lane, j1 = 2 * lane + 1;
    float a0 = __hip_atomic_load(Ac + (size_t)j0 * NCH + ch, __ATOMIC_ACQUIRE, __HIP_MEMORY_SCOPE_AGENT);
    float c0 = __hip_atomic_load(Cc + (size_t)j0 * NCH + ch, __ATOMIC_ACQUIRE, __HIP_MEMORY_SCOPE_AGENT);
    float a1 = __hip_atomic_load(Ac + (size_t)j1 * NCH + ch, __ATOMIC_ACQUIRE, __HIP_MEMORY_SCOPE_AGENT);
    float c1 = __hip_atomic_load(Cc + (size_t)j1 * NCH + ch, __ATOMIC_ACQUIRE, __HIP_MEMORY_SCOPE_AGENT);
    float a = a0 * a1;
    float c = fmaf(a1, c0, c1);
#pragma unroll
    for (int d = 1; d < 64; d <<= 1) {
      float pa = __shfl_up(a, d, 64);
      float pc = __shfl_up(c, d, 64);
      if (lane >= d) { c = fmaf(a, pc, c); a *= pa; }
    }
    float xa = __shfl_up(a, 1, 64), xc = __shfl_up(c, 1, 64);
    if (lane == 0) { xa = 1.0f; xc = 0.0f; }
    float h0 = hidden[ch];
    float hs0 = fmaf(xa, h0, xc);
    __hip_atomic_store(Hs + (size_t)j0 * NCH + ch, hs0, __ATOMIC_RELEASE, __HIP_MEMORY_SCOPE_AGENT);
    __hip_atomic_store(Hs + (size_t)j1 * NCH + ch, fmaf(a0, hs0, c0), __ATOMIC_RELEASE, __HIP_MEMORY_SCOPE_AGENT);
  }
  gridbar(bar + 1, 256);

  // phase C: replay from registers, write fp32 H (+ h_last)
  {
    const size_t o = (size_t)j * NCH + 2 * ch2;
    float h0 = __hip_atomic_load(Hs + o,     __ATOMIC_ACQUIRE, __HIP_MEMORY_SCOPE_AGENT);
    float h1 = __hip_atomic_load(Hs + o + 1, __ATOMIC_ACQUIRE, __HIP_MEMORY_SCOPE_AGENT);
    float* op = out + base;
#pragma unroll
    for (int i = 0; i < CHUNK; ++i) {
      unsigned fv = fr[i], zv = zr[i];
      h0 = fmaf(bf2f_lo(fv), bf2f_lo(zv) - h0, h0);
      h1 = fmaf(bf2f_hi(fv), bf2f_hi(zv) - h1, h1);
      float2 ov = {h0, h1};
      *(float2*)(op + (size_t)i * NCH) = ov;
    }
    if (j == NCHUNK - 1) {
      float2 ov = {h0, h1};
      *(float2*)(out + (size_t)SEQn * NCH + 2 * ch2) = ov;   // h_last row
    }
  }
}

extern "C" void kernel_launch(void* const* d_in, const int* in_sizes, int n_in,
                              void* d_out, int out_size, void* d_ws, size_t ws_size,
                              hipStream_t stream) {
  const float* X      = (const float*)d_in[0];
  const float* hidden = (const float*)d_in[1];
  const float* Wz     = (const float*)d_in[2];
  const float* bz     = (const float*)d_in[3];
  const float* Wf     = (const float*)d_in[4];
  const float* bfb    = (const float*)d_in[5];
  float* out = (float*)d_out;

  char* ws = (char*)d_ws;
  ushort* zbf = (ushort*)ws;                       // 16,777,216 B
  ushort* fbf = (ushort*)(ws + 16777216);          // 16,777,216 B
  ushort* Xbf = (ushort*)(ws + 33554432);          // 16,781,312 B (dead after gemm)
  ushort* Bm  = (ushort*)(ws + 50335744);          //    524,288 B
  unsigned* bar = (unsigned*)(ws + 50860032);      //          8 B
  // aliased over Xbf (used only after gemm completes):
  float* Ac = (float*)(ws + 33554432);
  float* Cc = (float*)(ws + 34603008);
  float* Hs = (float*)(ws + 35651584);

  pack_kernel<<<9218, 256, 0, stream>>>(X, Wz, Wf, Xbf, Bm, bar);
  dim3 ggrid(256, 2);
  gemm_kernel<<<ggrid, 256, 0, stream>>>(Xbf, Bm, bz, bfb, zbf, fbf);
  scan_kernel<<<256, 512, 0, stream>>>(zbf, fbf, hidden, Ac, Cc, Hs, out, bar);
}

// Round 5
// 164.038 us; speedup vs baseline: 2.2640x; 2.2640x over previous
//
#include <hip/hip_runtime.h>

// QRNN: SEQ=4096, BATCH=8, CIN=256, HID=256, K=2 (lookback=1)
// R5: R3 structure (5 kernels), but GEMM writes RAW z,f bf16 (no bias/activation);
//     bias+QuickGELU/sigmoid moved into scanA/scanC where VALU is idle.
//
// ws: zbf 16MB | fbf 16MB | Xbf 16MB (dead after gemm; Ac/Cc/Hs aliased) | Bm 0.5MB

#define SEQn 4096
#define NCH 2048          // BATCH*HID channels
#define CHUNK 32
#define NCHUNK 128

typedef __attribute__((ext_vector_type(8))) short bf16x8;
typedef __attribute__((ext_vector_type(4))) float floatx4;

__device__ __forceinline__ unsigned short f2bf(float x) {
  unsigned int u = __float_as_uint(x);
  u += 0x7fffu + ((u >> 16) & 1u);     // RNE
  return (unsigned short)(u >> 16);
}
__device__ __forceinline__ float bf2f(ushort u) {
  return __uint_as_float((unsigned int)u << 16);
}
__device__ __forceinline__ float sigf(float x) {
  return __builtin_amdgcn_rcpf(1.0f + __expf(-x));
}
__device__ __forceinline__ float qgelu(float x) {
  return x * sigf(1.702f * x);
}

// ---- 1) merged pack: blocks [0,1024) pack W, rest pack X ----
__global__ void pack_kernel(const float* __restrict__ X,
                            const float* __restrict__ Wz, const float* __restrict__ Wf,
                            ushort* __restrict__ Xbf, ushort* __restrict__ Bm) {
  if (blockIdx.x < 1024) {
    int idx = blockIdx.x * 256 + threadIdx.x;        // 0..262143
    int n = idx >> 9, kin = idx & 511;
    const float* W = (n < 256) ? Wz : Wf;
    int h = n & 255, c = kin & 255, tap = kin >> 8;  // kin<256: tap0 (X[s-1])
    Bm[idx] = f2bf(W[h * 512 + c * 2 + tap]);
  } else {
    int idx = (blockIdx.x - 1024) * 256 + threadIdx.x;
    const int total4 = ((SEQn + 1) * NCH) / 4;       // 2,097,664
    if (idx >= total4) return;
    const int pad4 = NCH / 4;
    float4 v;
    if (idx < pad4) { v.x = 0.f; v.y = 0.f; v.z = 0.f; v.w = 0.f; }
    else v = ((const float4*)X)[idx - pad4];
    ushort4 o;
    o.x = f2bf(v.x); o.y = f2bf(v.y); o.z = f2bf(v.z); o.w = f2bf(v.w);
    ((ushort4*)Xbf)[idx] = o;
  }
}

// ---- 2) GEMM 128x128, BK=64, mfma_f32_16x16x32_bf16, swizzled LDS ----
// LDS seg (row, s) holds global k-seg s^(row&7)  (seg = 16B = 8 bf16)
__global__ __launch_bounds__(256) void gemm_kernel(
    const ushort* __restrict__ Xbf, const ushort* __restrict__ Bm,
    ushort* __restrict__ zout, ushort* __restrict__ fout) {
  __shared__ __align__(16) char smem_raw[32768];
  ushort* sA = (ushort*)smem_raw;                 // 128 rows x 64 k
  ushort* sB = (ushort*)(smem_raw + 16384);       // 128 cols x 64 k
  ushort* sT = (ushort*)smem_raw;                 // epilogue 64 x 136

  const int tid  = threadIdx.x;
  const int wave = tid >> 6;
  const int lane = tid & 63;
  const int quad = lane >> 4;
  const int lrow = lane & 15;
  const int wm = wave >> 1;          // 2x2 wave grid, 64x64 each
  const int wn = wave & 1;
  const int bm = blockIdx.x;         // 0..255
  const int bn = blockIdx.y;         // 0..3 (0,1=Z; 2,3=F)

  floatx4 acc[4][4];
#pragma unroll
  for (int i = 0; i < 4; ++i)
#pragma unroll
    for (int j = 0; j < 4; ++j)
      acc[i][j] = (floatx4){0.f, 0.f, 0.f, 0.f};

  // staging coords: 4 segs each for A and B per thread
  int rowS[4], gko[4];               // LDS row, swizzled global k-seg offset
#pragma unroll
  for (int it = 0; it < 4; ++it) {
    int g = wave * 256 + it * 64 + lane;     // LDS seg index 0..1023
    int row = g >> 3, ks8 = g & 7;
    rowS[it] = row;
    gko[it] = (ks8 ^ (row & 7)) * 8;
  }
  char* ldsA = (char*)sA + wave * 4096 + (lane << 4);
  char* ldsB = (char*)sB + wave * 4096 + (lane << 4);

  for (int k0 = 0; k0 < 512; k0 += 64) {
    __syncthreads();                 // prev iter ds_reads done
#pragma unroll
    for (int it = 0; it < 4; ++it) {
      const int kk = k0 + gko[it];
      const int cA = (kk < 256) ? kk : kk + 1792;     // tap1 lives +2048-256
      __builtin_amdgcn_global_load_lds(
          (const __attribute__((address_space(1))) void*)(Xbf + (size_t)(bm * 128 + rowS[it]) * 256 + cA),
          (__attribute__((address_space(3))) void*)(ldsA + it * 1024), 16, 0, 0);
      __builtin_amdgcn_global_load_lds(
          (const __attribute__((address_space(1))) void*)(Bm + (size_t)(bn * 128 + rowS[it]) * 512 + kk),
          (__attribute__((address_space(3))) void*)(ldsB + it * 1024), 16, 0, 0);
    }
    __syncthreads();

    bf16x8 af[4][2], bfr[4][2];
#pragma unroll
    for (int fi = 0; fi < 4; ++fi) {
      const int r = wm * 64 + fi * 16 + lrow;
#pragma unroll
      for (int ks = 0; ks < 2; ++ks) {
        const int s = (ks * 4 + quad) ^ (r & 7);
        af[fi][ks] = *(const bf16x8*)&sA[r * 64 + s * 8];
      }
    }
#pragma unroll
    for (int fj = 0; fj < 4; ++fj) {
      const int r = wn * 64 + fj * 16 + lrow;
#pragma unroll
      for (int ks = 0; ks < 2; ++ks) {
        const int s = (ks * 4 + quad) ^ (r & 7);
        bfr[fj][ks] = *(const bf16x8*)&sB[r * 64 + s * 8];
      }
    }
#pragma unroll
    for (int ks = 0; ks < 2; ++ks)
#pragma unroll
      for (int fi = 0; fi < 4; ++fi)
#pragma unroll
        for (int fj = 0; fj < 4; ++fj)
          acc[fi][fj] = __builtin_amdgcn_mfma_f32_16x16x32_bf16(af[fi][ks], bfr[fj][ks], acc[fi][fj], 0, 0, 0);
  }

  // epilogue (raw): f2bf -> sT (64 x 136 padded) -> coalesced dwordx4
  const bool isZ = (bn < 2);
  ushort* gout = isZ ? zout : fout;
  const int ncol0 = (bn & 1) * 128;

  for (int round = 0; round < 2; ++round) {
    __syncthreads();
    if (wm == round) {
#pragma unroll
      for (int fi = 0; fi < 4; ++fi)
#pragma unroll
        for (int fj = 0; fj < 4; ++fj)
#pragma unroll
          for (int r = 0; r < 4; ++r)
            sT[(fi * 16 + quad * 4 + r) * 136 + wn * 64 + fj * 16 + lrow] = f2bf(acc[fi][fj][r]);
    }
    __syncthreads();
#pragma unroll
    for (int it = 0; it < 4; ++it) {
      int e = tid + it * 256;           // 1024 segs = 64 rows x 16 segs
      int row = e >> 4, seg = e & 15;
      uint4 v = *(uint4*)&sT[row * 136 + seg * 8];
      *(uint4*)(gout + (size_t)(bm * 128 + round * 64 + row) * 256 + ncol0 + seg * 8) = v;
    }
  }
}

// ---- 3) per-chunk reduction, 2 channels/thread, fused bias+activation ----
__global__ void scanA_kernel(const ushort* __restrict__ z, const ushort* __restrict__ f,
                             const float* __restrict__ bz, const float* __restrict__ bfb,
                             float* __restrict__ Ac, float* __restrict__ Cc) {
  int t = blockIdx.x * blockDim.x + threadIdx.x;   // 0..131071
  int ch2 = t & 1023;
  int j = t >> 10;                                  // 0..127
  const int h0 = (2 * ch2) & 255, h1 = h0 + 1;      // ch0 even -> h1 = h0+1
  const float zb0 = bz[h0], zb1 = bz[h1];
  const float fb0 = bfb[h0], fb1 = bfb[h1];
  const size_t base = (size_t)j * CHUNK * NCH + 2 * ch2;
  const ushort* zp = z + base;
  const ushort* fp = f + base;
  float A0 = 1.0f, C0 = 0.0f, A1 = 1.0f, C1 = 0.0f;
#pragma unroll
  for (int i = 0; i < CHUNK; ++i) {
    ushort2 fv = *(const ushort2*)(fp + (size_t)i * NCH);
    ushort2 zv = *(const ushort2*)(zp + (size_t)i * NCH);
    float f0 = sigf(bf2f(fv.x) + fb0), f1 = sigf(bf2f(fv.y) + fb1);
    float z0 = qgelu(bf2f(zv.x) + zb0), z1 = qgelu(bf2f(zv.y) + zb1);
    float a0 = 1.0f - f0, a1 = 1.0f - f1;
    C0 = fmaf(a0, C0, f0 * z0); A0 *= a0;
    C1 = fmaf(a1, C1, f1 * z1); A1 *= a1;
  }
  float2 Av = {A0, A1}, Cv = {C0, C1};
  *(float2*)(Ac + (size_t)j * NCH + 2 * ch2) = Av;
  *(float2*)(Cc + (size_t)j * NCH + 2 * ch2) = Cv;
}

// ---- 4) cross-chunk scan: one wave per channel, shfl Hillis-Steele ----
__global__ void scanB_kernel(const float* __restrict__ hidden,
                             const float* __restrict__ Ac, const float* __restrict__ Cc,
                             float* __restrict__ Hs) {
  const int lane = threadIdx.x & 63;
  const int ch = blockIdx.x * 4 + (threadIdx.x >> 6);   // 512 blocks x 4 waves
  const int j0 = 2 * lane, j1 = 2 * lane + 1;
  float a0 = Ac[j0 * NCH + ch], c0 = Cc[j0 * NCH + ch];
  float a1 = Ac[j1 * NCH + ch], c1 = Cc[j1 * NCH + ch];
  float a = a0 * a1;
  float c = fmaf(a1, c0, c1);
#pragma unroll
  for (int d = 1; d < 64; d <<= 1) {
    float pa = __shfl_up(a, d, 64);
    float pc = __shfl_up(c, d, 64);
    if (lane >= d) { c = fmaf(a, pc, c); a *= pa; }
  }
  float xa = __shfl_up(a, 1, 64), xc = __shfl_up(c, 1, 64);
  if (lane == 0) { xa = 1.0f; xc = 0.0f; }
  float h0 = hidden[ch];
  float hs0 = fmaf(xa, h0, xc);
  Hs[j0 * NCH + ch] = hs0;
  Hs[j1 * NCH + ch] = fmaf(a0, hs0, c0);
}

// ---- 5) replay within chunk, 2 channels/thread, fused bias+activation ----
__global__ void scanC_kernel(const ushort* __restrict__ z, const ushort* __restrict__ f,
                             const float* __restrict__ bz, const float* __restrict__ bfb,
                             const float* __restrict__ Hs, float* __restrict__ out) {
  int t = blockIdx.x * blockDim.x + threadIdx.x;   // 0..131071
  int ch2 = t & 1023;
  int j = t >> 10;
  const int h0i = (2 * ch2) & 255, h1i = h0i + 1;
  const float zb0 = bz[h0i], zb1 = bz[h1i];
  const float fb0 = bfb[h0i], fb1 = bfb[h1i];
  float2 hv = *(const float2*)(Hs + (size_t)j * NCH + 2 * ch2);
  float h0 = hv.x, h1 = hv.y;
  const size_t base = (size_t)j * CHUNK * NCH + 2 * ch2;
  const ushort* zp = z + base;
  const ushort* fp = f + base;
  float* op = out + base;
#pragma unroll
  for (int i = 0; i < CHUNK; ++i) {
    ushort2 fv = *(const ushort2*)(fp + (size_t)i * NCH);
    ushort2 zv = *(const ushort2*)(zp + (size_t)i * NCH);
    float f0 = sigf(bf2f(fv.x) + fb0), f1 = sigf(bf2f(fv.y) + fb1);
    float z0 = qgelu(bf2f(zv.x) + zb0), z1 = qgelu(bf2f(zv.y) + zb1);
    h0 = fmaf(f0, z0 - h0, h0);
    h1 = fmaf(f1, z1 - h1, h1);
    float2 o = {h0, h1};
    *(float2*)(op + (size_t)i * NCH) = o;
  }
  if (j == NCHUNK - 1) {
    float2 o = {h0, h1};
    *(float2*)(out + (size_t)SEQn * NCH + 2 * ch2) = o;   // h_last row
  }
}

extern "C" void kernel_launch(void* const* d_in, const int* in_sizes, int n_in,
                              void* d_out, int out_size, void* d_ws, size_t ws_size,
                              hipStream_t stream) {
  const float* X      = (const float*)d_in[0];
  const float* hidden = (const float*)d_in[1];
  const float* Wz     = (const float*)d_in[2];
  const float* bz     = (const float*)d_in[3];
  const float* Wf     = (const float*)d_in[4];
  const float* bfb    = (const float*)d_in[5];
  float* out = (float*)d_out;

  char* ws = (char*)d_ws;
  ushort* zbf = (ushort*)ws;                       // 16,777,216 B
  ushort* fbf = (ushort*)(ws + 16777216);          // 16,777,216 B
  ushort* Xbf = (ushort*)(ws + 33554432);          // 16,781,312 B (dead after gemm)
  ushort* Bm  = (ushort*)(ws + 50335744);          //    524,288 B
  // aliased over Xbf (used only after gemm completes):
  float* Ac = (float*)(ws + 33554432);
  float* Cc = (float*)(ws + 34603008);
  float* Hs = (float*)(ws + 35651584);

  pack_kernel<<<9218, 256, 0, stream>>>(X, Wz, Wf, Xbf, Bm);
  dim3 ggrid(256, 4);
  gemm_kernel<<<ggrid, 256, 0, stream>>>(Xbf, Bm, zbf, fbf);
  scanA_kernel<<<512, 256, 0, stream>>>(zbf, fbf, bz, bfb, Ac, Cc);
  scanB_kernel<<<512, 256, 0, stream>>>(hidden, Ac, Cc, Hs);
  scanC_kernel<<<512, 256, 0, stream>>>(zbf, fbf, bz, bfb, Hs, out);
}